// Round 1
// baseline (221.990 us; speedup 1.0000x reference)
//
#include <hip/hip_runtime.h>

// PaddedToSegments: batched stream compaction.
//   inputs: [B=16, T=2048, D=1024] f32
//   mask:   [B, T] bool (arrives as int32 per harness integer convention)
// Outputs flattened into one f32 buffer in return order:
//   collected [B,T,D] f32, valid_idx [B,T] (as float, -1 tail), counts [B] (as float)

#define BB 16
#define TT 2048
#define DD 1024

// ---------------------------------------------------------------------------
// Kernel 1: per-sample mask scan + compaction index build.
// One block per batch sample, 256 threads, each thread owns 8 consecutive t.
// ---------------------------------------------------------------------------
__global__ __launch_bounds__(256) void scan_kernel(
    const int* __restrict__ mask,
    float* __restrict__ out_vidx,    // [B,T] as float
    float* __restrict__ out_counts,  // [B]  as float
    int* __restrict__ ws_src,        // [B,T] compacted source row index
    int* __restrict__ ws_cnt)        // [B]
{
    const int b = blockIdx.x;
    const int tid = threadIdx.x;
    const int* m = mask + b * TT;

    // Load 8 mask values per thread, per-thread sum.
    int vals[8];
    int s = 0;
#pragma unroll
    for (int i = 0; i < 8; ++i) {
        vals[i] = (m[tid * 8 + i] != 0) ? 1 : 0;
        s += vals[i];
    }

    // Block-wide inclusive scan of per-thread sums (Hillis-Steele in LDS).
    __shared__ int sdata[256];
    sdata[tid] = s;
    __syncthreads();
#pragma unroll
    for (int off = 1; off < 256; off <<= 1) {
        int v = (tid >= off) ? sdata[tid - off] : 0;
        __syncthreads();
        sdata[tid] += v;
        __syncthreads();
    }
    const int excl = sdata[tid] - s;      // exclusive prefix for this thread
    const int total = sdata[255];         // valid count for this sample

    // Scatter compacted indices + valid_idx values.
    int pos = excl;
#pragma unroll
    for (int i = 0; i < 8; ++i) {
        if (vals[i]) {
            const int t = tid * 8 + i;
            ws_src[b * TT + pos] = t;
            out_vidx[b * TT + pos] = (float)t;
            ++pos;
        }
    }

    // Fill tail of valid_idx with -1.
    for (int c = total + tid; c < TT; c += 256) {
        out_vidx[b * TT + c] = -1.0f;
    }

    if (tid == 0) {
        ws_cnt[b] = total;
        out_counts[b] = (float)total;
    }
}

// ---------------------------------------------------------------------------
// Kernel 2: row gather / zero-fill. One block per output row (b, c).
// 256 threads x float4 = 4096 B = one full row per block, fully coalesced.
// ---------------------------------------------------------------------------
__global__ __launch_bounds__(256) void gather_kernel(
    const float* __restrict__ in,
    const int* __restrict__ ws_src,
    const int* __restrict__ ws_cnt,
    float* __restrict__ out)
{
    const int row = blockIdx.x;        // b*T + c
    const int b = row >> 11;           // / TT
    const int c = row & (TT - 1);
    const int tid = threadIdx.x;

    float4* dst = (float4*)(out + (size_t)row * DD);
    if (c < ws_cnt[b]) {
        const int src = ws_src[row];
        const float4* s = (const float4*)(in + ((size_t)b * TT + src) * DD);
        dst[tid] = s[tid];
    } else {
        dst[tid] = make_float4(0.f, 0.f, 0.f, 0.f);
    }
}

extern "C" void kernel_launch(void* const* d_in, const int* in_sizes, int n_in,
                              void* d_out, int out_size, void* d_ws, size_t ws_size,
                              hipStream_t stream) {
    const float* inputs = (const float*)d_in[0];
    const int* mask = (const int*)d_in[1];

    float* out = (float*)d_out;
    float* out_collected = out;                       // B*T*D
    float* out_vidx = out + (size_t)BB * TT * DD;     // B*T
    float* out_counts = out_vidx + (size_t)BB * TT;   // B

    int* ws_src = (int*)d_ws;          // B*T ints
    int* ws_cnt = ws_src + BB * TT;    // B ints

    scan_kernel<<<BB, 256, 0, stream>>>(mask, out_vidx, out_counts, ws_src, ws_cnt);
    gather_kernel<<<BB * TT, 256, 0, stream>>>(inputs, ws_src, ws_cnt, out_collected);
}

// Round 3
// 218.014 us; speedup vs baseline: 1.0182x; 1.0182x over previous
//
#include <hip/hip_runtime.h>

// PaddedToSegments: batched stream compaction.
//   inputs: [B=16, T=2048, D=1024] f32
//   mask:   [B, T] bool (arrives as int32 per harness integer convention)
// Outputs flattened into one f32 buffer in return order:
//   collected [B,T,D] f32, valid_idx [B,T] (as float, -1 tail), counts [B] (as float)

#define BB 16
#define TT 2048
#define DD 1024
#define ROW4 (DD / 4)   // 256 float4 per row

// Native Clang vector type: accepted by __builtin_nontemporal_* (HIP's float4
// is a class and is rejected).
typedef float f4 __attribute__((ext_vector_type(4)));

// ---------------------------------------------------------------------------
// Kernel 1: per-sample mask scan + compaction index build.
// One block per batch sample, 256 threads, each thread owns 8 consecutive t
// (loaded as two int4).
// ---------------------------------------------------------------------------
__global__ __launch_bounds__(256) void scan_kernel(
    const int* __restrict__ mask,
    float* __restrict__ out_vidx,    // [B,T] as float
    float* __restrict__ out_counts,  // [B]  as float
    int* __restrict__ ws_src,        // [B,T] compacted source row index
    int* __restrict__ ws_cnt)        // [B]
{
    const int b = blockIdx.x;
    const int tid = threadIdx.x;
    const int4* m4 = (const int4*)(mask + b * TT);

    // Load 8 mask values per thread (2x int4), per-thread sum.
    int4 a0 = m4[tid * 2];
    int4 a1 = m4[tid * 2 + 1];
    int vals[8];
    vals[0] = (a0.x != 0); vals[1] = (a0.y != 0);
    vals[2] = (a0.z != 0); vals[3] = (a0.w != 0);
    vals[4] = (a1.x != 0); vals[5] = (a1.y != 0);
    vals[6] = (a1.z != 0); vals[7] = (a1.w != 0);
    int s = 0;
#pragma unroll
    for (int i = 0; i < 8; ++i) s += vals[i];

    // Block-wide inclusive scan of per-thread sums (Hillis-Steele in LDS).
    __shared__ int sdata[256];
    sdata[tid] = s;
    __syncthreads();
#pragma unroll
    for (int off = 1; off < 256; off <<= 1) {
        int v = (tid >= off) ? sdata[tid - off] : 0;
        __syncthreads();
        sdata[tid] += v;
        __syncthreads();
    }
    const int excl = sdata[tid] - s;      // exclusive prefix for this thread
    const int total = sdata[255];         // valid count for this sample

    // Scatter compacted indices + valid_idx values.
    int pos = excl;
#pragma unroll
    for (int i = 0; i < 8; ++i) {
        if (vals[i]) {
            const int t = tid * 8 + i;
            ws_src[b * TT + pos] = t;
            out_vidx[b * TT + pos] = (float)t;
            ++pos;
        }
    }

    // Fill tail of valid_idx with -1.
    for (int c = total + tid; c < TT; c += 256) {
        out_vidx[b * TT + c] = -1.0f;
    }

    if (tid == 0) {
        ws_cnt[b] = total;
        out_counts[b] = (float)total;
    }
}

// ---------------------------------------------------------------------------
// Kernel 2: row gather / zero-fill.
// Each block handles 8 consecutive output rows; 32 lanes per row; each thread
// issues 8 independent float4 loads (ILP=8) before storing. Non-temporal
// loads/stores keep the 192 MB stream out of L2's way.
// ---------------------------------------------------------------------------
__global__ __launch_bounds__(256) void gather_kernel(
    const f4* __restrict__ in,     // [B*T][256] f4
    const int* __restrict__ ws_src,
    const int* __restrict__ ws_cnt,
    f4* __restrict__ out)          // [B*T][256] f4
{
    const int tid  = threadIdx.x;
    const int lrow = tid >> 5;                  // 0..7 local row
    const int lane = tid & 31;                  // 0..31
    const int row  = blockIdx.x * 8 + lrow;     // b*T + c  (same b for whole block)
    const int b    = row >> 11;                 // / TT
    const int c    = row & (TT - 1);

    f4* dst = out + (size_t)row * ROW4;
    if (c < ws_cnt[b]) {
        const int src = ws_src[row];
        const f4* sp = in + ((size_t)(b << 11) + (size_t)src) * ROW4;
        f4 v[8];
#pragma unroll
        for (int j = 0; j < 8; ++j)
            v[j] = __builtin_nontemporal_load(sp + lane + j * 32);
#pragma unroll
        for (int j = 0; j < 8; ++j)
            __builtin_nontemporal_store(v[j], dst + lane + j * 32);
    } else {
        const f4 z = {0.f, 0.f, 0.f, 0.f};
#pragma unroll
        for (int j = 0; j < 8; ++j)
            __builtin_nontemporal_store(z, dst + lane + j * 32);
    }
}

extern "C" void kernel_launch(void* const* d_in, const int* in_sizes, int n_in,
                              void* d_out, int out_size, void* d_ws, size_t ws_size,
                              hipStream_t stream) {
    const float* inputs = (const float*)d_in[0];
    const int* mask = (const int*)d_in[1];

    float* out = (float*)d_out;
    float* out_collected = out;                       // B*T*D
    float* out_vidx = out + (size_t)BB * TT * DD;     // B*T
    float* out_counts = out_vidx + (size_t)BB * TT;   // B

    int* ws_src = (int*)d_ws;          // B*T ints
    int* ws_cnt = ws_src + BB * TT;    // B ints

    scan_kernel<<<BB, 256, 0, stream>>>(mask, out_vidx, out_counts, ws_src, ws_cnt);
    gather_kernel<<<BB * TT / 8, 256, 0, stream>>>(
        (const f4*)inputs, ws_src, ws_cnt, (f4*)out_collected);
}